// Round 12
// baseline (269.699 us; speedup 1.0000x reference)
//
#include <hip/hip_runtime.h>
#include <stdint.h>

#define BATCH 4
#define SEQ 2048
#define DMODEL 1024
#define NHEADS 16
#define HDIM 64

typedef __attribute__((ext_vector_type(4))) short short4v;
typedef __attribute__((ext_vector_type(4))) float float4v;
typedef __attribute__((ext_vector_type(4))) int int4v;
typedef __attribute__((ext_vector_type(2))) unsigned int uint2v;
typedef __attribute__((ext_vector_type(4))) unsigned int uint4v;
typedef __attribute__((ext_vector_type(4))) unsigned short ushort4v;
typedef __attribute__((ext_vector_type(8))) __bf16 bf16x8;

union FragAB { short4v h[2]; unsigned int u[4]; bf16x8 v; };

// 0.125 * log2(e)  (folded into Q rope so softmax runs in exp2 domain)
#define QSCALE 0.18033688011112042f
// theta^(-2i/64) = 2^(-i * 2*log2(10000)/64)
#define ROPE_L2 -0.41524101186092030f

__device__ __forceinline__ float bf2f(unsigned short u){
  union { unsigned int i; float f; } v; v.i = ((unsigned int)u) << 16; return v.f;
}
__device__ __forceinline__ unsigned short f2bf(float f){
  union { unsigned int i; float f; } v; v.f = f;
  unsigned int x = v.i;
  return (unsigned short)((x + 0x7FFFu + ((x >> 16) & 1u)) >> 16);
}

// async global -> LDS, 16B per lane. LDS dest: wave-uniform base + lane*16.
__device__ __forceinline__ void gload16(const unsigned short* g, unsigned short* l){
  __builtin_amdgcn_global_load_lds(
      (const __attribute__((address_space(1))) void*)g,
      (__attribute__((address_space(3))) void*)l, 16, 0, 0);
}

// ---------------- fused fp32 -> bf16 conversion: x + all 4 weights ----------------
__global__ void cvt_all(const float* __restrict__ x,
                        const float* __restrict__ Wq, const float* __restrict__ Wk,
                        const float* __restrict__ Wv, const float* __restrict__ Wo,
                        unsigned short* __restrict__ x_bf, unsigned short* __restrict__ w_bf){
  int idx = blockIdx.x * 256 + threadIdx.x;   // 3145728 float4s total
  const float* src;
  unsigned short* dst;
  int i;
  if (idx < 2097152){
    src = x; dst = x_bf; i = idx;
  } else {
    int widx = idx - 2097152;
    int mat = widx >> 18;
    i = widx & 262143;
    src = (mat == 0) ? Wq : (mat == 1) ? Wk : (mat == 2) ? Wv : Wo;
    dst = w_bf + (size_t)mat * 1048576;
  }
  float4v f = ((const float4v*)src)[i];
  ushort4v o;
  o[0]=f2bf(f[0]); o[1]=f2bf(f[1]); o[2]=f2bf(f[2]); o[3]=f2bf(f[3]);
  ((ushort4v*)dst)[i] = o;
}

// ---------------- bf16 GEMM 128x128 tile, BK=32, 3-buffer counted-vmcnt pipeline ----
// 1-D grid, XCD-aware swizzle. MODE 0 (QKV, NBX=24): m-fast/n-slow within XCD so the
// XCD's 8 A-panels (2 MB) stay L2-resident while B streams once (6 MB).
// MODE 1: fp32 row-major Fd (final O-projection, NBX=8), n-fast (4 MB total, fits).
template<int MODE, int NBX>
__launch_bounds__(256, 3)
__global__ void gemm_cnt(const unsigned short* __restrict__ A,
                         const unsigned short* __restrict__ W,
                         unsigned short* __restrict__ Qd,
                         unsigned short* __restrict__ Kd,
                         unsigned short* __restrict__ Vd,
                         float* __restrict__ Fd,
                         const int* __restrict__ pos)
{
  __shared__ __align__(16) unsigned short Al[3][128][32];
  __shared__ __align__(16) unsigned short Bl[3][128][32];

  const int tid  = threadIdx.x;
  const int wid  = tid >> 6, lane = tid & 63;
  const int lg   = lane >> 4, lr = lane & 15;
  const int wm   = wid >> 1, wn = wid & 1;

  const int nblk = blockIdx.x;
  const int xcd  = nblk & 7, jj = nblk >> 3;
  const int m0   = (MODE == 0) ? (xcd * 8 + (jj & 7)) * 128 : (xcd * 8 + jj / NBX) * 128;
  const int n0   = (MODE == 0) ? (jj >> 3) * 128          : (jj % NBX) * 128;

  const unsigned short* Ab = A + (size_t)(m0 + wid*32 + (lane >> 2)) * DMODEL + (lane & 3) * 8;
  const unsigned short* Wb = W + (size_t)(n0 + wid*32 + (lane >> 2)) * DMODEL + (lane & 3) * 8;

  float4v acc[4][4] = {};
  const int nt = DMODEL / 32;   // 32

  #define STAGE_G(bufi, kofs) do{                                          \
    gload16(Ab + (kofs),                 &Al[bufi][wid*32][0]);             \
    gload16(Ab + (size_t)16*DMODEL + (kofs), &Al[bufi][wid*32 + 16][0]);    \
    gload16(Wb + (kofs),                 &Bl[bufi][wid*32][0]);             \
    gload16(Wb + (size_t)16*DMODEL + (kofs), &Bl[bufi][wid*32 + 16][0]);    \
  }while(0)

  STAGE_G(0, 0);
  STAGE_G(1, 32);

  int bc = 0;   // compute buffer = t % 3
  #pragma unroll 1
  for (int t = 0; t < nt; ++t){
    if (t < nt - 1) asm volatile("s_waitcnt vmcnt(4)" ::: "memory");
    else            asm volatile("s_waitcnt vmcnt(0)" ::: "memory");
    __builtin_amdgcn_s_barrier();

    if (t + 2 < nt){
      int bs = bc + 2; if (bs >= 3) bs -= 3;
      STAGE_G(bs, (t + 2) * 32);
    }

    FragAB afr[4], bfr[4];
    #pragma unroll
    for (int f = 0; f < 4; ++f){
      afr[f].v = *(const bf16x8*)&Al[bc][wm*64 + f*16 + lr][lg*8];
      bfr[f].v = *(const bf16x8*)&Bl[bc][wn*64 + f*16 + lr][lg*8];
    }
    #pragma unroll
    for (int fm = 0; fm < 4; ++fm)
      #pragma unroll
      for (int fn = 0; fn < 4; ++fn)
        acc[fm][fn] = __builtin_amdgcn_mfma_f32_16x16x32_bf16(afr[fm].v, bfr[fn].v, acc[fm][fn], 0, 0, 0);

    bc = (bc == 2) ? 0 : bc + 1;
  }
  #undef STAGE_G

  #pragma unroll
  for (int fm = 0; fm < 4; ++fm)
    #pragma unroll
    for (int fn = 0; fn < 4; ++fn){
      const int gm = m0 + wm*64 + fm*16 + lg*4;   // +r
      const int gn = n0 + wn*64 + fn*16 + lr;
      if (MODE == 1){
        float* op = Fd + (size_t)gm * DMODEL + gn;
        #pragma unroll
        for (int r = 0; r < 4; ++r) op[(size_t)r * DMODEL] = acc[fm][fn][r];
      } else {
        const int mat = gn >> 10;
        const int b = gm >> 11, s = gm & (SEQ - 1);
        const int h = (gn >> 6) & (NHEADS - 1), d = gn & (HDIM - 1);
        if (mat == 2){
          unsigned short* op = Vd + (((size_t)(b*NHEADS + h))*HDIM + d)*SEQ + s;
          uint2v pk2;
          pk2[0] = (unsigned int)f2bf(acc[fm][fn][0]) | ((unsigned int)f2bf(acc[fm][fn][1]) << 16);
          pk2[1] = (unsigned int)f2bf(acc[fm][fn][2]) | ((unsigned int)f2bf(acc[fm][fn][3]) << 16);
          *(uint2v*)op = pk2;
        } else {
          // fused RoPE: pair (d even, d odd) sits in lanes lr^1
          int4v p4v = *(const int4v*)(pos + s);
          const float invf = exp2f(ROPE_L2 * (float)(d >> 1));
          const float sgn  = (d & 1) ? 1.f : -1.f;
          const float scl  = (mat == 0) ? QSCALE : 1.0f;
          unsigned short* op = (mat == 0 ? Qd : Kd) + (((size_t)(b*NHEADS + h))*SEQ + s)*HDIM + d;
          #pragma unroll
          for (int r = 0; r < 4; ++r){
            float v  = acc[fm][fn][r];
            float pv = __shfl_xor(v, 1);
            float ang = (float)p4v[r] * invf;
            float sn, cs;
            __sincosf(ang, &sn, &cs);
            op[(size_t)r * HDIM] = f2bf((v*cs + pv*sn*sgn) * scl);
          }
        }
      }
    }
}

// ---------------- MFMA causal flash attention v9 ----------------
// Round-8 per-wave body, UN-PAIRED: grid 2048 = one block per (bh, qtb),
// long q-tiles dispatched first. Single-buffer K/V LDS (18.4 KB) with T14
// split staging (issue loads early, ds_write after post-compute barrier):
// 8 blocks/CU = 32 waves/CU, cross-block overlap hides the serial chain.
// launch_bounds(256,8): VGPR cap 64 (measured use 56 -> no spill).
__launch_bounds__(256, 8)
__global__ void flash_attn9(const unsigned short* __restrict__ Qg,
                            const unsigned short* __restrict__ Kg,
                            const unsigned short* __restrict__ VTg,
                            unsigned short* __restrict__ Og)
{
  __shared__ __align__(16) unsigned short Kl[64][72];
  __shared__ __align__(16) unsigned short Vt[64][72];

  const int tid  = threadIdx.x;
  const int w    = tid >> 6, lane = tid & 63;
  const int lg   = lane >> 4, lr = lane & 15;

  const int nblk = blockIdx.x;
  const int xcd  = nblk & 7, jj = nblk >> 3;   // jj: 0..255
  const int bh   = xcd + ((jj & 7) << 3);
  const int qtb  = 31 - (jj >> 3);             // 31..0, long q-tiles first

  const size_t baseK = (size_t)bh * SEQ * HDIM;
  const size_t baseV = (size_t)bh * HDIM * SEQ;
  const int b = bh >> 4, h = bh & (NHEADS - 1);

  const int sr  = tid >> 3;        // 0..31
  const int sc8 = (tid & 7) * 8;   // 0..56

  const int nt    = qtb + 1;
  const int qglob = qtb * 64 + w * 16 + lr;

  // Q frags (B operand), contiguous sigma: chunk c holds d = c*32 + lg*8 + j
  FragAB qf[2];
  {
    const unsigned short* qrow = Qg + baseK + (size_t)qglob * HDIM;
    qf[0].v = *(const bf16x8*)(qrow + lg*8);
    qf[1].v = *(const bf16x8*)(qrow + 32 + lg*8);
  }

  float4v o[4] = {};
  float mrun = -1e30f, lrun = 0.f;

  uint4v kreg[2], vreg[2];
  #pragma unroll
  for (int p = 0; p < 2; ++p){
    kreg[p] = *(const uint4v*)(Kg  + baseK + (size_t)(p*32 + sr) * HDIM + sc8);
    vreg[p] = *(const uint4v*)(VTg + baseV + (size_t)(p*32 + sr) * SEQ + sc8);
  }
  #pragma unroll
  for (int p = 0; p < 2; ++p){
    *(uint4v*)&Kl[p*32 + sr][sc8] = kreg[p];
    *(uint4v*)&Vt[p*32 + sr][sc8] = vreg[p];
  }
  __syncthreads();

  #pragma unroll 1
  for (int t = 0; t < nt; ++t){
    const int nxt = t + 1;
    if (nxt < nt){
      const int kv1 = nxt * 64;
      #pragma unroll
      for (int p = 0; p < 2; ++p){
        kreg[p] = *(const uint4v*)(Kg  + baseK + (size_t)(kv1 + p*32 + sr) * HDIM + sc8);
        vreg[p] = *(const uint4v*)(VTg + baseV + (size_t)(p*32 + sr) * SEQ + kv1 + sc8);
      }
    }

    {
      const int kv0 = t * 64;
      const bool diag = (t == qtb);
      float p4[4][4];

      __builtin_amdgcn_s_setprio(1);
      #pragma unroll
      for (int kb = 0; kb < 4; ++kb){
        const unsigned short* krow = &Kl[kb*16 + lr][0];
        FragAB kf0, kf1;
        kf0.v = *(const bf16x8*)(krow + lg*8);
        kf1.v = *(const bf16x8*)(krow + 32 + lg*8);
        float4v st = {};
        st = __builtin_amdgcn_mfma_f32_16x16x32_bf16(kf0.v, qf[0].v, st, 0, 0, 0);
        st = __builtin_amdgcn_mfma_f32_16x16x32_bf16(kf1.v, qf[1].v, st, 0, 0, 0);
        if (diag){
          #pragma unroll
          for (int r = 0; r < 4; ++r)
            p4[kb][r] = (kv0 + kb*16 + lg*4 + r <= qglob) ? st[r] : -1e30f;
        } else {
          #pragma unroll
          for (int r = 0; r < 4; ++r) p4[kb][r] = st[r];
        }
      }
      __builtin_amdgcn_s_setprio(0);

      float rmax = p4[0][0];
      #pragma unroll
      for (int kb = 0; kb < 4; ++kb)
        #pragma unroll
        for (int r = 0; r < 4; ++r) rmax = fmaxf(rmax, p4[kb][r]);
      rmax = fmaxf(rmax, __shfl_xor(rmax, 16));
      rmax = fmaxf(rmax, __shfl_xor(rmax, 32));

      if (__any(rmax > mrun + 11.5f)){   // defer-max, exp2 domain
        float mnew  = fmaxf(mrun, rmax);
        float alpha = exp2f(mrun - mnew);
        lrun *= alpha;
        #pragma unroll
        for (int dm = 0; dm < 4; ++dm)
          #pragma unroll
          for (int r = 0; r < 4; ++r) o[dm][r] *= alpha;
        mrun = mnew;
      }
      float rsum = 0.f;
      #pragma unroll
      for (int kb = 0; kb < 4; ++kb)
        #pragma unroll
        for (int r = 0; r < 4; ++r){
          float e = exp2f(p4[kb][r] - mrun);
          p4[kb][r] = e;
          rsum += e;
        }
      rsum += __shfl_xor(rsum, 16);
      rsum += __shfl_xor(rsum, 32);
      lrun += rsum;

      // P -> bf16 frags: pf[kc].h[0] = p4[2kc][j] (k=lg*4+j), h[1] = p4[2kc+1][j]
      FragAB pf[2];
      #pragma unroll
      for (int kc = 0; kc < 2; ++kc){
        unsigned int u0, u1, u2, u3;
        asm("v_cvt_pk_bf16_f32 %0, %1, %2" : "=v"(u0) : "v"(p4[2*kc][0]),   "v"(p4[2*kc][1]));
        asm("v_cvt_pk_bf16_f32 %0, %1, %2" : "=v"(u1) : "v"(p4[2*kc][2]),   "v"(p4[2*kc][3]));
        asm("v_cvt_pk_bf16_f32 %0, %1, %2" : "=v"(u2) : "v"(p4[2*kc+1][0]), "v"(p4[2*kc+1][1]));
        asm("v_cvt_pk_bf16_f32 %0, %1, %2" : "=v"(u3) : "v"(p4[2*kc+1][2]), "v"(p4[2*kc+1][3]));
        pf[kc].u[0] = u0; pf[kc].u[1] = u1; pf[kc].u[2] = u2; pf[kc].u[3] = u3;
      }

      __builtin_amdgcn_s_setprio(1);
      #pragma unroll
      for (int dm = 0; dm < 4; ++dm){
        const unsigned short* vrow = &Vt[dm*16 + lr][0];
        #pragma unroll
        for (int kc = 0; kc < 2; ++kc){
          FragAB vf;   // split sigma matches pf construction
          vf.h[0] = *(const short4v*)(vrow + kc*32 + lg*4);
          vf.h[1] = *(const short4v*)(vrow + kc*32 + 16 + lg*4);
          o[dm] = __builtin_amdgcn_mfma_f32_16x16x32_bf16(vf.v, pf[kc].v, o[dm], 0, 0, 0);
        }
      }
      __builtin_amdgcn_s_setprio(0);
    }

    __syncthreads();            // all waves done reading tile t
    if (nxt < nt){
      #pragma unroll
      for (int p = 0; p < 2; ++p){
        *(uint4v*)&Kl[p*32 + sr][sc8] = kreg[p];
        *(uint4v*)&Vt[p*32 + sr][sc8] = vreg[p];
      }
      __syncthreads();          // writes visible before next reads
    }
  }

  const float inv = 1.0f / lrun;
  unsigned short* orow = Og + ((size_t)(b*SEQ + qglob)) * DMODEL + h*HDIM;
  #pragma unroll
  for (int dm = 0; dm < 4; ++dm){
    uint2v pkd;
    pkd[0] = (unsigned int)f2bf(o[dm][0]*inv) | ((unsigned int)f2bf(o[dm][1]*inv) << 16);
    pkd[1] = (unsigned int)f2bf(o[dm][2]*inv) | ((unsigned int)f2bf(o[dm][3]*inv) << 16);
    *(uint2v*)(orow + dm*16 + lg*4) = pkd;
  }
}

// ---------------- launch ----------------
extern "C" void kernel_launch(void* const* d_in, const int* in_sizes, int n_in,
                              void* d_out, int out_size, void* d_ws, size_t ws_size,
                              hipStream_t stream)
{
  const float* x  = (const float*)d_in[0];
  const float* Wq = (const float*)d_in[1];
  const float* Wk = (const float*)d_in[2];
  const float* Wv = (const float*)d_in[3];
  const float* Wo = (const float*)d_in[4];
  const int* tpos = (const int*)d_in[5];

  char* w = (char*)d_ws;
  const size_t XBF = 16777216;   // 8192*1024*2
  const size_t WBF = 2097152;    // 1024*1024*2
  unsigned short* x_bf  = (unsigned short*)(w);
  unsigned short* wq_bf = (unsigned short*)(w + XBF);
  unsigned short* wo_bf = (unsigned short*)(w + XBF + 3*WBF);
  unsigned short* Qb  = (unsigned short*)(w + XBF + 4*WBF);
  unsigned short* Kb  = (unsigned short*)(w + XBF + 4*WBF + XBF);
  unsigned short* VTb = (unsigned short*)(w + XBF + 4*WBF + 2*XBF);
  unsigned short* Ab  = (unsigned short*)(w + XBF + 4*WBF + 3*XBF);

  cvt_all<<<12288, 256, 0, stream>>>(x, Wq, Wk, Wv, Wo, x_bf, wq_bf);

  // fused QKV projection + RoPE (N = 3072), XCD-swizzled, m-fast/n-slow
  gemm_cnt<0, 24><<<1536, 256, 0, stream>>>(x_bf, wq_bf, Qb, Kb, VTb, nullptr, tpos);

  flash_attn9<<<2048, 256, 0, stream>>>(Qb, Kb, VTb, Ab);

  // final O-projection -> fp32 d_out, XCD-swizzled
  gemm_cnt<1, 8><<<512, 256, 0, stream>>>(Ab, wo_bf, nullptr, nullptr, nullptr, (float*)d_out, tpos);
}

// Round 13
// 177.154 us; speedup vs baseline: 1.5224x; 1.5224x over previous
//
#include <hip/hip_runtime.h>
#include <stdint.h>

#define BATCH 4
#define SEQ 2048
#define DMODEL 1024
#define NHEADS 16
#define HDIM 64

typedef __attribute__((ext_vector_type(4))) short short4v;
typedef __attribute__((ext_vector_type(4))) float float4v;
typedef __attribute__((ext_vector_type(4))) int int4v;
typedef __attribute__((ext_vector_type(2))) unsigned int uint2v;
typedef __attribute__((ext_vector_type(4))) unsigned int uint4v;
typedef __attribute__((ext_vector_type(4))) unsigned short ushort4v;
typedef __attribute__((ext_vector_type(8))) __bf16 bf16x8;

union FragAB { short4v h[2]; unsigned int u[4]; bf16x8 v; };

// 0.125 * log2(e)  (folded into Q rope so softmax runs in exp2 domain)
#define QSCALE 0.18033688011112042f
// theta^(-2i/64) = 2^(-i * 2*log2(10000)/64)
#define ROPE_L2 -0.41524101186092030f

__device__ __forceinline__ float bf2f(unsigned short u){
  union { unsigned int i; float f; } v; v.i = ((unsigned int)u) << 16; return v.f;
}
__device__ __forceinline__ unsigned short f2bf(float f){
  union { unsigned int i; float f; } v; v.f = f;
  unsigned int x = v.i;
  return (unsigned short)((x + 0x7FFFu + ((x >> 16) & 1u)) >> 16);
}

// async global -> LDS, 16B per lane. LDS dest: wave-uniform base + lane*16.
__device__ __forceinline__ void gload16(const unsigned short* g, unsigned short* l){
  __builtin_amdgcn_global_load_lds(
      (const __attribute__((address_space(1))) void*)g,
      (__attribute__((address_space(3))) void*)l, 16, 0, 0);
}

// ---------------- fused fp32 -> bf16 conversion: x + all 4 weights ----------------
__global__ void cvt_all(const float* __restrict__ x,
                        const float* __restrict__ Wq, const float* __restrict__ Wk,
                        const float* __restrict__ Wv, const float* __restrict__ Wo,
                        unsigned short* __restrict__ x_bf, unsigned short* __restrict__ w_bf){
  int idx = blockIdx.x * 256 + threadIdx.x;   // 3145728 float4s total
  const float* src;
  unsigned short* dst;
  int i;
  if (idx < 2097152){
    src = x; dst = x_bf; i = idx;
  } else {
    int widx = idx - 2097152;
    int mat = widx >> 18;
    i = widx & 262143;
    src = (mat == 0) ? Wq : (mat == 1) ? Wk : (mat == 2) ? Wv : Wo;
    dst = w_bf + (size_t)mat * 1048576;
  }
  float4v f = ((const float4v*)src)[i];
  ushort4v o;
  o[0]=f2bf(f[0]); o[1]=f2bf(f[1]); o[2]=f2bf(f[2]); o[3]=f2bf(f[3]);
  ((ushort4v*)dst)[i] = o;
}

// ---------------- bf16 GEMM 128x128 tile, BK=32, 3-buffer counted-vmcnt pipeline ----
// 1-D grid, XCD-aware swizzle. MODE 0 (QKV, NBX=24): m-fast/n-slow within XCD so the
// XCD's 8 A-panels (2 MB) stay L2-resident while B streams once (6 MB).
// MODE 1: fp32 row-major Fd (final O-projection, NBX=8), n-fast (4 MB total, fits).
template<int MODE, int NBX>
__launch_bounds__(256, 3)
__global__ void gemm_cnt(const unsigned short* __restrict__ A,
                         const unsigned short* __restrict__ W,
                         unsigned short* __restrict__ Qd,
                         unsigned short* __restrict__ Kd,
                         unsigned short* __restrict__ Vd,
                         float* __restrict__ Fd,
                         const int* __restrict__ pos)
{
  __shared__ __align__(16) unsigned short Al[3][128][32];
  __shared__ __align__(16) unsigned short Bl[3][128][32];

  const int tid  = threadIdx.x;
  const int wid  = tid >> 6, lane = tid & 63;
  const int lg   = lane >> 4, lr = lane & 15;
  const int wm   = wid >> 1, wn = wid & 1;

  const int nblk = blockIdx.x;
  const int xcd  = nblk & 7, jj = nblk >> 3;
  const int m0   = (MODE == 0) ? (xcd * 8 + (jj & 7)) * 128 : (xcd * 8 + jj / NBX) * 128;
  const int n0   = (MODE == 0) ? (jj >> 3) * 128          : (jj % NBX) * 128;

  const unsigned short* Ab = A + (size_t)(m0 + wid*32 + (lane >> 2)) * DMODEL + (lane & 3) * 8;
  const unsigned short* Wb = W + (size_t)(n0 + wid*32 + (lane >> 2)) * DMODEL + (lane & 3) * 8;

  float4v acc[4][4] = {};
  const int nt = DMODEL / 32;   // 32

  #define STAGE_G(bufi, kofs) do{                                          \
    gload16(Ab + (kofs),                 &Al[bufi][wid*32][0]);             \
    gload16(Ab + (size_t)16*DMODEL + (kofs), &Al[bufi][wid*32 + 16][0]);    \
    gload16(Wb + (kofs),                 &Bl[bufi][wid*32][0]);             \
    gload16(Wb + (size_t)16*DMODEL + (kofs), &Bl[bufi][wid*32 + 16][0]);    \
  }while(0)

  STAGE_G(0, 0);
  STAGE_G(1, 32);

  int bc = 0;   // compute buffer = t % 3
  #pragma unroll 1
  for (int t = 0; t < nt; ++t){
    if (t < nt - 1) asm volatile("s_waitcnt vmcnt(4)" ::: "memory");
    else            asm volatile("s_waitcnt vmcnt(0)" ::: "memory");
    __builtin_amdgcn_s_barrier();

    if (t + 2 < nt){
      int bs = bc + 2; if (bs >= 3) bs -= 3;
      STAGE_G(bs, (t + 2) * 32);
    }

    FragAB afr[4], bfr[4];
    #pragma unroll
    for (int f = 0; f < 4; ++f){
      afr[f].v = *(const bf16x8*)&Al[bc][wm*64 + f*16 + lr][lg*8];
      bfr[f].v = *(const bf16x8*)&Bl[bc][wn*64 + f*16 + lr][lg*8];
    }
    #pragma unroll
    for (int fm = 0; fm < 4; ++fm)
      #pragma unroll
      for (int fn = 0; fn < 4; ++fn)
        acc[fm][fn] = __builtin_amdgcn_mfma_f32_16x16x32_bf16(afr[fm].v, bfr[fn].v, acc[fm][fn], 0, 0, 0);

    bc = (bc == 2) ? 0 : bc + 1;
  }
  #undef STAGE_G

  #pragma unroll
  for (int fm = 0; fm < 4; ++fm)
    #pragma unroll
    for (int fn = 0; fn < 4; ++fn){
      const int gm = m0 + wm*64 + fm*16 + lg*4;   // +r
      const int gn = n0 + wn*64 + fn*16 + lr;
      if (MODE == 1){
        float* op = Fd + (size_t)gm * DMODEL + gn;
        #pragma unroll
        for (int r = 0; r < 4; ++r) op[(size_t)r * DMODEL] = acc[fm][fn][r];
      } else {
        const int mat = gn >> 10;
        const int b = gm >> 11, s = gm & (SEQ - 1);
        const int h = (gn >> 6) & (NHEADS - 1), d = gn & (HDIM - 1);
        if (mat == 2){
          unsigned short* op = Vd + (((size_t)(b*NHEADS + h))*HDIM + d)*SEQ + s;
          uint2v pk2;
          pk2[0] = (unsigned int)f2bf(acc[fm][fn][0]) | ((unsigned int)f2bf(acc[fm][fn][1]) << 16);
          pk2[1] = (unsigned int)f2bf(acc[fm][fn][2]) | ((unsigned int)f2bf(acc[fm][fn][3]) << 16);
          *(uint2v*)op = pk2;
        } else {
          // fused RoPE: pair (d even, d odd) sits in lanes lr^1
          int4v p4v = *(const int4v*)(pos + s);
          const float invf = exp2f(ROPE_L2 * (float)(d >> 1));
          const float sgn  = (d & 1) ? 1.f : -1.f;
          const float scl  = (mat == 0) ? QSCALE : 1.0f;
          unsigned short* op = (mat == 0 ? Qd : Kd) + (((size_t)(b*NHEADS + h))*SEQ + s)*HDIM + d;
          #pragma unroll
          for (int r = 0; r < 4; ++r){
            float v  = acc[fm][fn][r];
            float pv = __shfl_xor(v, 1);
            float ang = (float)p4v[r] * invf;
            float sn, cs;
            __sincosf(ang, &sn, &cs);
            op[(size_t)r * HDIM] = f2bf((v*cs + pv*sn*sgn) * scl);
          }
        }
      }
    }
}

// ---------------- MFMA causal flash attention v10 ----------------
// Round-8 proven body (512 thr, 8 waves x 16 q-rows, stride-72 LDS, reg dbuf,
// VGPR 44 @ (512,4) -> no spill), UN-PAIRED: grid 1024 = one block per
// (bh, qtb), long q-tiles dispatched first. LDS 36.9KB + VGPR 44 both permit
// 4 blocks/CU = 32 waves/CU; the doubled co-residency hides the serial
// QK->softmax->PV chain. XCD swizzle keeps each bh's K/V L2-resident.
__launch_bounds__(512, 4)
__global__ void flash_attn10(const unsigned short* __restrict__ Qg,
                             const unsigned short* __restrict__ Kg,
                             const unsigned short* __restrict__ VTg,
                             unsigned short* __restrict__ Og)
{
  __shared__ __align__(16) unsigned short Kl[2][64][72];
  __shared__ __align__(16) unsigned short Vt[2][64][72];

  const int tid  = threadIdx.x;
  const int w    = tid >> 6, lane = tid & 63;
  const int lg   = lane >> 4, lr = lane & 15;

  const int nblk = blockIdx.x;
  const int xcd  = nblk & 7, jj = nblk >> 3;   // jj: 0..127
  const int bh   = xcd + ((jj & 7) << 3);
  const int qtb  = 15 - (jj >> 3);             // 15..0, long q-tiles first

  const size_t baseK = (size_t)bh * SEQ * HDIM;
  const size_t baseV = (size_t)bh * HDIM * SEQ;
  const int b = bh >> 4, h = bh & (NHEADS - 1);

  const int sr  = tid >> 3;        // 0..63
  const int sc8 = (tid & 7) * 8;   // 0..56

  const int q0    = qtb * 128;
  const int qmin  = q0 + w * 16;
  const int wlast = qmin >> 6;
  const int nt    = 2 * qtb + 2;
  const int qglob = qmin + lr;

  // Q frags (B operand), contiguous sigma: chunk c holds d = c*32 + lg*8 + j
  FragAB qf[2];
  {
    const unsigned short* qrow = Qg + baseK + (size_t)qglob * HDIM;
    qf[0].v = *(const bf16x8*)(qrow + lg*8);
    qf[1].v = *(const bf16x8*)(qrow + 32 + lg*8);
  }

  float4v o[4] = {};
  float mrun = -1e30f, lrun = 0.f;

  uint4v kreg, vreg;
  kreg = *(const uint4v*)(Kg  + baseK + (size_t)sr * HDIM + sc8);
  vreg = *(const uint4v*)(VTg + baseV + (size_t)sr * SEQ + sc8);
  *(uint4v*)&Kl[0][sr][sc8] = kreg;
  *(uint4v*)&Vt[0][sr][sc8] = vreg;
  __syncthreads();

  int buf = 0;
  #pragma unroll 1
  for (int t = 0; t < nt; ++t){
    const int nxt = t + 1;
    if (nxt < nt){
      const int kv1 = nxt * 64;
      kreg = *(const uint4v*)(Kg  + baseK + (size_t)(kv1 + sr) * HDIM + sc8);
      vreg = *(const uint4v*)(VTg + baseV + (size_t)sr * SEQ + kv1 + sc8);
    }

    if (t <= wlast){
      const int kv0 = t * 64;
      const bool diag = (t == wlast);
      float p4[4][4];

      __builtin_amdgcn_s_setprio(1);
      #pragma unroll
      for (int kb = 0; kb < 4; ++kb){
        const unsigned short* krow = &Kl[buf][kb*16 + lr][0];
        FragAB kf0, kf1;
        kf0.v = *(const bf16x8*)(krow + lg*8);
        kf1.v = *(const bf16x8*)(krow + 32 + lg*8);
        float4v st = {};
        st = __builtin_amdgcn_mfma_f32_16x16x32_bf16(kf0.v, qf[0].v, st, 0, 0, 0);
        st = __builtin_amdgcn_mfma_f32_16x16x32_bf16(kf1.v, qf[1].v, st, 0, 0, 0);
        if (diag){
          #pragma unroll
          for (int r = 0; r < 4; ++r)
            p4[kb][r] = (kv0 + kb*16 + lg*4 + r <= qglob) ? st[r] : -1e30f;
        } else {
          #pragma unroll
          for (int r = 0; r < 4; ++r) p4[kb][r] = st[r];
        }
      }
      __builtin_amdgcn_s_setprio(0);

      float rmax = p4[0][0];
      #pragma unroll
      for (int kb = 0; kb < 4; ++kb)
        #pragma unroll
        for (int r = 0; r < 4; ++r) rmax = fmaxf(rmax, p4[kb][r]);
      rmax = fmaxf(rmax, __shfl_xor(rmax, 16));
      rmax = fmaxf(rmax, __shfl_xor(rmax, 32));

      if (__any(rmax > mrun + 11.5f)){   // defer-max, exp2 domain
        float mnew  = fmaxf(mrun, rmax);
        float alpha = exp2f(mrun - mnew);
        lrun *= alpha;
        #pragma unroll
        for (int dm = 0; dm < 4; ++dm)
          #pragma unroll
          for (int r = 0; r < 4; ++r) o[dm][r] *= alpha;
        mrun = mnew;
      }
      float rsum = 0.f;
      #pragma unroll
      for (int kb = 0; kb < 4; ++kb)
        #pragma unroll
        for (int r = 0; r < 4; ++r){
          float e = exp2f(p4[kb][r] - mrun);
          p4[kb][r] = e;
          rsum += e;
        }
      rsum += __shfl_xor(rsum, 16);
      rsum += __shfl_xor(rsum, 32);
      lrun += rsum;

      // P -> bf16 frags: pf[kc].h[0] = p4[2kc][j] (k=lg*4+j), h[1] = p4[2kc+1][j]
      FragAB pf[2];
      #pragma unroll
      for (int kc = 0; kc < 2; ++kc){
        unsigned int u0, u1, u2, u3;
        asm("v_cvt_pk_bf16_f32 %0, %1, %2" : "=v"(u0) : "v"(p4[2*kc][0]),   "v"(p4[2*kc][1]));
        asm("v_cvt_pk_bf16_f32 %0, %1, %2" : "=v"(u1) : "v"(p4[2*kc][2]),   "v"(p4[2*kc][3]));
        asm("v_cvt_pk_bf16_f32 %0, %1, %2" : "=v"(u2) : "v"(p4[2*kc+1][0]), "v"(p4[2*kc+1][1]));
        asm("v_cvt_pk_bf16_f32 %0, %1, %2" : "=v"(u3) : "v"(p4[2*kc+1][2]), "v"(p4[2*kc+1][3]));
        pf[kc].u[0] = u0; pf[kc].u[1] = u1; pf[kc].u[2] = u2; pf[kc].u[3] = u3;
      }

      __builtin_amdgcn_s_setprio(1);
      #pragma unroll
      for (int dm = 0; dm < 4; ++dm){
        const unsigned short* vrow = &Vt[buf][dm*16 + lr][0];
        #pragma unroll
        for (int kc = 0; kc < 2; ++kc){
          FragAB vf;   // split sigma matches pf construction
          vf.h[0] = *(const short4v*)(vrow + kc*32 + lg*4);
          vf.h[1] = *(const short4v*)(vrow + kc*32 + 16 + lg*4);
          o[dm] = __builtin_amdgcn_mfma_f32_16x16x32_bf16(vf.v, pf[kc].v, o[dm], 0, 0, 0);
        }
      }
      __builtin_amdgcn_s_setprio(0);
    }

    if (nxt < nt){
      *(uint4v*)&Kl[buf^1][sr][sc8] = kreg;
      *(uint4v*)&Vt[buf^1][sr][sc8] = vreg;
    }
    __syncthreads();
    buf ^= 1;
  }

  const float inv = 1.0f / lrun;
  unsigned short* orow = Og + ((size_t)(b*SEQ + qglob)) * DMODEL + h*HDIM;
  #pragma unroll
  for (int dm = 0; dm < 4; ++dm){
    uint2v pkd;
    pkd[0] = (unsigned int)f2bf(o[dm][0]*inv) | ((unsigned int)f2bf(o[dm][1]*inv) << 16);
    pkd[1] = (unsigned int)f2bf(o[dm][2]*inv) | ((unsigned int)f2bf(o[dm][3]*inv) << 16);
    *(uint2v*)(orow + dm*16 + lg*4) = pkd;
  }
}

// ---------------- launch ----------------
extern "C" void kernel_launch(void* const* d_in, const int* in_sizes, int n_in,
                              void* d_out, int out_size, void* d_ws, size_t ws_size,
                              hipStream_t stream)
{
  const float* x  = (const float*)d_in[0];
  const float* Wq = (const float*)d_in[1];
  const float* Wk = (const float*)d_in[2];
  const float* Wv = (const float*)d_in[3];
  const float* Wo = (const float*)d_in[4];
  const int* tpos = (const int*)d_in[5];

  char* w = (char*)d_ws;
  const size_t XBF = 16777216;   // 8192*1024*2
  const size_t WBF = 2097152;    // 1024*1024*2
  unsigned short* x_bf  = (unsigned short*)(w);
  unsigned short* wq_bf = (unsigned short*)(w + XBF);
  unsigned short* wo_bf = (unsigned short*)(w + XBF + 3*WBF);
  unsigned short* Qb  = (unsigned short*)(w + XBF + 4*WBF);
  unsigned short* Kb  = (unsigned short*)(w + XBF + 4*WBF + XBF);
  unsigned short* VTb = (unsigned short*)(w + XBF + 4*WBF + 2*XBF);
  unsigned short* Ab  = (unsigned short*)(w + XBF + 4*WBF + 3*XBF);

  cvt_all<<<12288, 256, 0, stream>>>(x, Wq, Wk, Wv, Wo, x_bf, wq_bf);

  // fused QKV projection + RoPE (N = 3072), XCD-swizzled, m-fast/n-slow
  gemm_cnt<0, 24><<<1536, 256, 0, stream>>>(x_bf, wq_bf, Qb, Kb, VTb, nullptr, tpos);

  flash_attn10<<<1024, 512, 0, stream>>>(Qb, Kb, VTb, Ab);

  // final O-projection -> fp32 d_out, XCD-swizzled
  gemm_cnt<1, 8><<<512, 256, 0, stream>>>(Ab, wo_bf, nullptr, nullptr, nullptr, (float*)d_out, tpos);
}